// Round 1
// baseline (311.809 us; speedup 1.0000x reference)
//
#include <hip/hip_runtime.h>

// TSB RNN: per-row affine scan over T=4096 steps, wave-parallel via
// (anti-diagonal per-step linear part) => (diagonal over step-pairs) =>
// two independent 1-D affine scans (p,u) and (q,v).
//
// One wave (64 lanes) per batch row; lane owns 64 contiguous timesteps.

constexpr int T_LEN = 4096;
constexpr int CHUNK = 64;              // timesteps per lane
constexpr int WAVES_PER_BLOCK = 4;     // 256-thread blocks

__global__ __launch_bounds__(256) void tsb_scan_kernel(
    const float* __restrict__ x,      // (B, T)
    const float* __restrict__ alpha_p,
    const float* __restrict__ beta_p,
    float* __restrict__ out,          // (B, T)
    int B)
{
    const int tid  = threadIdx.x;
    const int wave = tid >> 6;
    const int lane = tid & 63;
    const int row  = blockIdx.x * WAVES_PER_BLOCK + wave;
    if (row >= B) return;

    const float a   = alpha_p[0];
    const float b   = beta_p[0];
    const float oma = 1.0f - a;
    const float omb = 1.0f - b;

    const size_t row_off = (size_t)row * T_LEN + (size_t)lane * CHUNK;
    const float4* xp = (const float4*)(x + row_off);
    const float4* Xp = (const float4*)(x + (size_t)lane * CHUNK); // row 0 (shared X_t)

    // Keep own row chunk in registers (64 floats = 16 float4).
    float4 xv[16];
#pragma unroll
    for (int i = 0; i < 16; ++i) xv[i] = xp[i];

    // ---- Phase 1: local affine map over 64 steps (32 step-pairs) ----
    // c1 -> p*c1 + u ; c2 -> q*c2 + v
    float p = 1.f, u = 0.f, q = 1.f, v = 0.f;
#pragma unroll
    for (int i = 0; i < 16; ++i) {
        float4 X4 = Xp[i];
        float4 x4 = xv[i];
        const float xs[4] = {x4.x, x4.y, x4.z, x4.w};
        const float Xs[4] = {X4.x, X4.y, X4.z, X4.w};
#pragma unroll
        for (int h = 0; h < 2; ++h) {           // two pairs per float4
            float x1 = xs[2*h],   x2 = xs[2*h+1];
            float X1 = Xs[2*h],   X2 = Xs[2*h+1];
            float nz1 = (x1 != 0.f) ? 1.f : 0.f;
            float nz2 = (x2 != 0.f) ? 1.f : 0.f;
            float k1  = (x1 != 0.f) ? oma : 1.f;
            float k2  = (x2 != 0.f) ? oma : 1.f;
            // pair map (step t then t+1):
            float P = omb * k1;
            float U = omb * a * nz1 * X1 + b * nz2;
            float Q = omb * k2;
            float V = b * k2 * nz1 + a * nz2 * X2;
            u = P * u + U;  p = P * p;
            v = Q * v + V;  q = Q * q;
        }
    }

    // ---- Phase 2: inclusive Hillis-Steele scan across 64 lanes ----
#pragma unroll
    for (int off = 1; off < 64; off <<= 1) {
        float p_in = __shfl_up(p, off, 64);
        float u_in = __shfl_up(u, off, 64);
        float q_in = __shfl_up(q, off, 64);
        float v_in = __shfl_up(v, off, 64);
        if (lane >= off) {
            u = p * u_in + u;  p = p * p_in;
            v = q * v_in + v;  q = q * q_in;
        }
    }
    // Entry state for this lane = exclusive prefix applied to (0,0) = (u,v) of lane-1.
    float c1 = __shfl_up(u, 1, 64);
    float c2 = __shfl_up(v, 1, 64);
    if (lane == 0) { c1 = 0.f; c2 = 0.f; }

    // ---- Phase 3: exact replay, emit out = c1'*c2' ----
    float4* op = (float4*)(out + row_off);
#pragma unroll
    for (int i = 0; i < 16; ++i) {
        float4 X4 = Xp[i];
        float4 x4 = xv[i];
        const float xs[4] = {x4.x, x4.y, x4.z, x4.w};
        const float Xs[4] = {X4.x, X4.y, X4.z, X4.w};
        float4 o;
        float os[4];
#pragma unroll
        for (int j = 0; j < 4; ++j) {
            float xj = xs[j];
            bool  nz = (xj != 0.f);
            float c2n = nz ? (a * Xs[j] + oma * c1) : c1;
            float c1n = (nz ? b : 0.f) + omb * c2;
            c1 = c1n; c2 = c2n;
            os[j] = c1 * c2;
        }
        o.x = os[0]; o.y = os[1]; o.z = os[2]; o.w = os[3];
        op[i] = o;
    }
}

extern "C" void kernel_launch(void* const* d_in, const int* in_sizes, int n_in,
                              void* d_out, int out_size, void* d_ws, size_t ws_size,
                              hipStream_t stream) {
    const float* x     = (const float*)d_in[0];
    const float* alpha = (const float*)d_in[1];
    const float* beta  = (const float*)d_in[2];
    float* out = (float*)d_out;

    const int B = in_sizes[0] / T_LEN;           // 8192
    const int blocks = (B + WAVES_PER_BLOCK - 1) / WAVES_PER_BLOCK;
    tsb_scan_kernel<<<blocks, 64 * WAVES_PER_BLOCK, 0, stream>>>(
        x, alpha, beta, out, B);
}

// Round 2
// 237.459 us; speedup vs baseline: 1.3131x; 1.3131x over previous
//
#include <hip/hip_runtime.h>

// TSB RNN, wave-per-row affine scan, LDS-transposed I/O.
//
// Per-step linear part is anti-diagonal => over step-PAIRS the map is
// diagonal: c1 -> P*c1 + U, c2 -> Q*c2 + V (independent 1-D affine scans).
// Wave (64 lanes) owns one row; processes T=4096 in 4 tiles of 1024 steps
// (16 steps/lane), carrying (C1,C2) across tiles.
//
// All global I/O is lane-stride-1 coalesced (float4); the global<->lane-chunk
// transpose goes through a per-wave private LDS region (+1 dword per 16
// elements => chunk reads at stride 17 = conflict-free-ish, 2-way max).
// No __syncthreads needed: LDS regions are wave-private, DS ops in-order.

constexpr int T_LEN  = 4096;
constexpr int TILE   = 1024;
constexpr int NTILE  = T_LEN / TILE;     // 4
constexpr int CHUNK  = TILE / 64;        // 16 steps per lane per tile
constexpr int WPB    = 4;                // waves per 256-thread block
constexpr int PADREG = TILE + TILE / 16; // 1088 dwords per padded region

__global__ __launch_bounds__(256) void tsb_scan_kernel(
    const float* __restrict__ x,       // (B, T)
    const float* __restrict__ alpha_p,
    const float* __restrict__ beta_p,
    float* __restrict__ out,           // (B, T)
    int B)
{
    __shared__ float lds[WPB * 2 * PADREG];   // 34,816 B / block

    const int tid  = threadIdx.x;
    const int wave = tid >> 6;
    const int lane = tid & 63;
    const int row  = blockIdx.x * WPB + wave;
    if (row >= B) return;

    float* xl = &lds[wave * 2 * PADREG];  // own-row tile (reused for output)
    float* Xl = xl + PADREG;              // row-0 tile (shared X_t quirk)

    const float a   = alpha_p[0];
    const float b   = beta_p[0];
    const float oma = 1.0f - a;
    const float omb = 1.0f - b;

    float C1 = 0.f, C2 = 0.f;             // carry across tiles

    for (int t = 0; t < NTILE; ++t) {
        const float4* xr4 = (const float4*)(x + (size_t)row * T_LEN + t * TILE);
        const float4* Xr4 = (const float4*)(x + t * TILE);

        // ---- coalesced global loads (4 lines/instr) ----
        float xs[16], Xs[16];
#pragma unroll
        for (int i = 0; i < 4; ++i) {
            *(float4*)(xs + 4 * i) = xr4[i * 64 + lane];
            *(float4*)(Xs + 4 * i) = Xr4[i * 64 + lane];
        }
        // ---- scatter to padded LDS ----
#pragma unroll
        for (int j = 0; j < 16; ++j) {
            int e  = (j >> 2) * 256 + 4 * lane + (j & 3); // element idx in tile
            int ap = e + (e >> 4);                        // padded addr
            xl[ap] = xs[j];
            Xl[ap] = Xs[j];
        }
        // ---- gather per-lane contiguous chunk (stride-17 base) ----
        float xc[CHUNK], Xc[CHUNK];
        const int cb = 17 * lane;
#pragma unroll
        for (int j = 0; j < CHUNK; ++j) {
            xc[j] = xl[cb + j];
            Xc[j] = Xl[cb + j];
        }

        // ---- phase 1: compose 8 step-pairs into (p,u | q,v) ----
        float p = 1.f, u = 0.f, q = 1.f, v = 0.f;
#pragma unroll
        for (int h = 0; h < CHUNK / 2; ++h) {
            float x1 = xc[2 * h], x2 = xc[2 * h + 1];
            float X1 = Xc[2 * h], X2 = Xc[2 * h + 1];
            float nz1 = (x1 != 0.f) ? 1.f : 0.f;
            float nz2 = (x2 != 0.f) ? 1.f : 0.f;
            float k1  = (x1 != 0.f) ? oma : 1.f;
            float k2  = (x2 != 0.f) ? oma : 1.f;
            float P = omb * k1;
            float U = omb * a * nz1 * X1 + b * nz2;
            float Q = omb * k2;
            float V = b * k2 * nz1 + a * nz2 * X2;
            u = P * u + U;  p = P * p;
            v = Q * v + V;  q = Q * q;
        }

        // ---- phase 2: inclusive shuffle scan over 64 lanes ----
#pragma unroll
        for (int off = 1; off < 64; off <<= 1) {
            float pi = __shfl_up(p, off, 64);
            float ui = __shfl_up(u, off, 64);
            float qi = __shfl_up(q, off, 64);
            float vi = __shfl_up(v, off, 64);
            if (lane >= off) {
                u = p * ui + u;  p = p * pi;
                v = q * vi + v;  q = q * qi;
            }
        }
        // lane entry state = exclusive prefix applied to tile carry
        float pp = __shfl_up(p, 1, 64), up = __shfl_up(u, 1, 64);
        float qp = __shfl_up(q, 1, 64), vp = __shfl_up(v, 1, 64);
        float c1 = (lane == 0) ? C1 : (pp * C1 + up);
        float c2 = (lane == 0) ? C2 : (qp * C2 + vp);
        // tile exit carry from lane 63's inclusive map (uses OLD C1,C2)
        float p63 = __shfl(p, 63, 64), u63 = __shfl(u, 63, 64);
        float q63 = __shfl(q, 63, 64), v63 = __shfl(v, 63, 64);
        float C1n = p63 * C1 + u63;
        float C2n = q63 * C2 + v63;
        C1 = C1n;  C2 = C2n;

        // ---- phase 3: exact replay; outputs overwrite own chunk in LDS ----
#pragma unroll
        for (int j = 0; j < CHUNK; ++j) {
            float xj = xc[j];
            bool  nz = (xj != 0.f);
            float c2n = nz ? (a * Xc[j] + oma * c1) : c1;
            float c1n = (nz ? b : 0.f) + omb * c2;
            c1 = c1n;  c2 = c2n;
            xl[cb + j] = c1 * c2;
        }

        // ---- coalesced global stores (full lines) ----
        float4* or4 = (float4*)(out + (size_t)row * T_LEN + t * TILE);
#pragma unroll
        for (int i = 0; i < 4; ++i) {
            float os[4];
#pragma unroll
            for (int k = 0; k < 4; ++k) {
                int e = i * 256 + 4 * lane + k;
                os[k] = xl[e + (e >> 4)];
            }
            or4[i * 64 + lane] = *(float4*)os;
        }
    }
}

extern "C" void kernel_launch(void* const* d_in, const int* in_sizes, int n_in,
                              void* d_out, int out_size, void* d_ws, size_t ws_size,
                              hipStream_t stream) {
    const float* x     = (const float*)d_in[0];
    const float* alpha = (const float*)d_in[1];
    const float* beta  = (const float*)d_in[2];
    float* out = (float*)d_out;

    const int B = in_sizes[0] / T_LEN;   // 8192
    const int blocks = (B + WPB - 1) / WPB;
    tsb_scan_kernel<<<blocks, 64 * WPB, 0, stream>>>(x, alpha, beta, out, B);
}